// Round 4
// baseline (1459.608 us; speedup 1.0000x reference)
//
#include <hip/hip_runtime.h>
#include <hip/hip_bf16.h>
#include <stdint.h>

// ---------------------------------------------------------------------------
// CapsuleNet forward, MI355X gfx950.  Round 4: dtype-agnostic I/O.
// A detector kernel decides at runtime whether float tensors are fp32 or bf16
// (flag in ws); all input reads and output writes branch on the flag.
// NaN clamps retained at stage boundaries. ws-adaptive conv chunking.
// ---------------------------------------------------------------------------

typedef short short8 __attribute__((ext_vector_type(8)));
typedef unsigned short u16x8 __attribute__((ext_vector_type(8)));
typedef float f32x4  __attribute__((ext_vector_type(4)));

__device__ inline float bf2f(unsigned short u) {
    unsigned int v = ((unsigned int)u) << 16;
    float f;
    __builtin_memcpy(&f, &v, 4);
    return f;
}
__device__ inline unsigned short f2bf(float f) {
    __hip_bfloat16 h = __float2bfloat16(f);
    unsigned short u;
    __builtin_memcpy(&u, &h, 2);
    return u;
}
__device__ inline float clampf(float x, float b) {   // scrubs NaN -> -b
    return fminf(fmaxf(x, -b), b);
}
// flag-aware float read: f=1 -> fp32 buffer, f=0 -> bf16 buffer
__device__ inline float rdf(const void* p, size_t i, int f) {
    return f ? ((const float*)p)[i] : bf2f(((const unsigned short*)p)[i]);
}

// ---------------------------------------------------------------------------
// Detect input float dtype from conv1_w (values ~N(0,0.05)).
// bf16 mode: all 256 halfwords decode small. fp32 mode: ~half of the low
// halfwords (raw mantissa bits) decode to |x|>100.
__global__ void k_detect(const void* w, int* flag) {
    int lane = threadIdx.x;                       // 64 threads
    const unsigned short* u = (const unsigned short*)w;
    int cnt = 0;
#pragma unroll
    for (int j = 0; j < 4; ++j) {
        float v = fabsf(bf2f(u[lane * 4 + j]));
        if (v > 100.f) cnt++;
    }
#pragma unroll
    for (int off = 32; off; off >>= 1) cnt += __shfl_xor(cnt, off);
    if (lane == 0) flag[0] = (cnt >= 4) ? 1 : 0;
}

// ---------------------------------------------------------------------------
__global__ void k_repack_w1(const void* __restrict__ w,
                            unsigned short* __restrict__ B1p,
                            const int* __restrict__ flagp) {
    int f = *flagp;
    int idx = blockIdx.x * 256 + threadIdx.x;      // 256*96
    int co = idx / 96, k = idx - co * 96;
    B1p[idx] = (k < 81) ? f2bf(rdf(w, (size_t)co * 81 + k, f)) : (unsigned short)0;
}

// pconv_w [co][ci][81] -> Bp2[t][co][ci] (bf16)
__global__ void k_repack_w2(const void* __restrict__ w,
                            unsigned short* __restrict__ Bp,
                            const int* __restrict__ flagp) {
    int f = *flagp;
    int idx = blockIdx.x * 256 + threadIdx.x;      // 81*65536
    int t = idx >> 16;
    int r = idx & 65535;
    int co = r >> 8, ci = r & 255;
    Bp[idx] = f2bf(rdf(w, (size_t)(co * 256 + ci) * 81 + t, f));
}

// ---------------------------------------------------------------------------
// conv1 chunk: local rows [0, C*400), images [b0, b0+C). A gathered from x.
// Frag layouts (m89/m91-verified): A: m=lane&15, k=(lane>>4)*8+j
//                                  B: n=lane&15, k=(lane>>4)*8+j
//                                  C: col=lane&15, row=(lane>>4)*4+reg
__global__ __launch_bounds__(256) void k_conv1(
        const void* __restrict__ x,
        const unsigned short* __restrict__ B1p,
        const void* __restrict__ bias,
        unsigned short* __restrict__ h1p, int b0,
        const int* __restrict__ flagp) {
    __shared__ int offt[96];
    int tid = threadIdx.x;
    if (tid < 96) offt[tid] = (tid < 81) ? (tid / 9) * 28 + (tid % 9) : 0;
    __syncthreads();
    int f = *flagp;

    int wave = tid >> 6, lane = tid & 63;
    int wr = wave >> 1, wc = wave & 1;
    int mbase = blockIdx.x * 128 + wr * 64;
    int nbase = blockIdx.y * 128 + wc * 64;
    int l15 = lane & 15, l4 = lane >> 4;

    int xb[4];
#pragma unroll
    for (int mt = 0; mt < 4; ++mt) {
        int m = mbase + mt * 16 + l15;
        int b = b0 + m / 400, pos = m % 400;
        xb[mt] = b * 784 + (pos / 20) * 28 + (pos % 20);
    }
    const float* xf = (const float*)x;
    const unsigned short* xu = (const unsigned short*)x;

    f32x4 acc[4][4];
#pragma unroll
    for (int mt = 0; mt < 4; ++mt)
#pragma unroll
        for (int nt = 0; nt < 4; ++nt)
            acc[mt][nt] = (f32x4){0.f, 0.f, 0.f, 0.f};

#pragma unroll
    for (int kc = 0; kc < 3; ++kc) {
        int kbase = kc * 32 + l4 * 8;
        short8 af[4], bfr[4];
#pragma unroll
        for (int mt = 0; mt < 4; ++mt)
#pragma unroll
            for (int j = 0; j < 8; ++j) {
                int k = kbase + j;
                short v = 0;
                if (k < 81) {
                    int idx = xb[mt] + offt[k];
                    v = f ? (short)f2bf(xf[idx]) : (short)xu[idx];
                }
                af[mt][j] = v;
            }
#pragma unroll
        for (int nt = 0; nt < 4; ++nt)
            bfr[nt] = *(const short8*)(B1p + (size_t)(nbase + nt * 16 + l15) * 96 + kbase);
#pragma unroll
        for (int mt = 0; mt < 4; ++mt)
#pragma unroll
            for (int nt = 0; nt < 4; ++nt)
                acc[mt][nt] = __builtin_amdgcn_mfma_f32_16x16x32_bf16(
                    af[mt], bfr[nt], acc[mt][nt], 0, 0, 0);
    }

#pragma unroll
    for (int mt = 0; mt < 4; ++mt)
#pragma unroll
        for (int nt = 0; nt < 4; ++nt) {
            int col = nbase + nt * 16 + l15;
            float bv = rdf(bias, col, f);
#pragma unroll
            for (int r = 0; r < 4; ++r) {
                int row = mbase + mt * 16 + l4 * 4 + r;
                h1p[(size_t)row * 256 + col] = f2bf(clampf(acc[mt][nt][r] + bv, 1024.f));
            }
        }
}

// ---------------------------------------------------------------------------
// conv2 chunk, implicit im2col, full K=20736. 64x128 tile (2x2 waves 32x64).
// local m = bb*36 + pos (bb in [0,C)); global h2 row = b0*36 + m. h2 bf16.
__global__ __launch_bounds__(256) void k_conv2(
        const unsigned short* __restrict__ h1p,
        const unsigned short* __restrict__ Bp,
        unsigned short* __restrict__ h2, int b0) {
    int tid = threadIdx.x;
    int wave = tid >> 6, lane = tid & 63;
    int wr = wave >> 1, wc = wave & 1;
    int mbase = blockIdx.x * 64 + wr * 32;
    int nbase = blockIdx.y * 128 + wc * 64;
    int l15 = lane & 15, l4 = lane >> 4;

    int rowoff[2];
#pragma unroll
    for (int mt = 0; mt < 2; ++mt) {
        int m = mbase + mt * 16 + l15;
        int bb = m / 36, pos = m - bb * 36;
        int y = pos / 6, xx = pos - y * 6;
        rowoff[mt] = (bb * 400 + y * 40 + xx * 2) * 256;   // (bb,2y,2x) NHWC base
    }
    int koff = l4 * 8;

    f32x4 acc[2][4];
#pragma unroll
    for (int mt = 0; mt < 2; ++mt)
#pragma unroll
        for (int nt = 0; nt < 4; ++nt)
            acc[mt][nt] = (f32x4){0.f, 0.f, 0.f, 0.f};

    for (int t = 0; t < 81; ++t) {
        int ky = t / 9, kx = t - ky * 9;
        int tadd = (ky * 20 + kx) * 256;
        const unsigned short* bb2 = Bp + ((size_t)t << 16) + (size_t)nbase * 256;
#pragma unroll
        for (int kc = 0; kc < 8; ++kc) {
            int k0 = kc * 32 + koff;
            short8 af[2], bfr[4];
#pragma unroll
            for (int mt = 0; mt < 2; ++mt)
                af[mt] = *(const short8*)(h1p + rowoff[mt] + tadd + k0);
#pragma unroll
            for (int nt = 0; nt < 4; ++nt)
                bfr[nt] = *(const short8*)(bb2 + (nt * 16 + l15) * 256 + k0);
#pragma unroll
            for (int mt = 0; mt < 2; ++mt)
#pragma unroll
                for (int nt = 0; nt < 4; ++nt)
                    acc[mt][nt] = __builtin_amdgcn_mfma_f32_16x16x32_bf16(
                        af[mt], bfr[nt], acc[mt][nt], 0, 0, 0);
        }
    }

#pragma unroll
    for (int mt = 0; mt < 2; ++mt)
#pragma unroll
        for (int nt = 0; nt < 4; ++nt) {
            int col = nbase + nt * 16 + l15;
#pragma unroll
            for (int r = 0; r < 4; ++r) {
                int row = b0 * 36 + mbase + mt * 16 + l4 * 4 + r;
                h2[(size_t)row * 256 + col] = f2bf(clampf(acc[mt][nt][r], 16384.f));
            }
        }
}

// ---------------------------------------------------------------------------
// +bias, regroup [b][co][pos] into caps of 8, squash -> caps bf16
__global__ void k_caps(const unsigned short* __restrict__ h2,
                       const void* __restrict__ pb,
                       unsigned short* __restrict__ caps,
                       const int* __restrict__ flagp) {
    int f = *flagp;
    int g = blockIdx.x * 256 + threadIdx.x;   // 256*1152
    int b = g / 1152, i = g - b * 1152;
    float h[8], ss = 0.f;
#pragma unroll
    for (int d = 0; d < 8; ++d) {
        int flat = i * 8 + d;                 // = co*36 + pos
        int co = flat / 36, pos = flat - co * 36;
        float v = clampf(bf2f(h2[(size_t)(b * 36 + pos) * 256 + co]) + rdf(pb, co, f), 20000.f);
        h[d] = v;
        ss += v * v;
    }
    float sc = sqrtf(ss) / (1.f + ss);        // norm/(1+norm^2)
    u16x8 cv;
#pragma unroll
    for (int d = 0; d < 8; ++d) cv[d] = f2bf(h[d] * sc);
    *(u16x8*)(caps + (size_t)g * 8) = cv;
}

// ---------------------------------------------------------------------------
// Dynamic routing. One block per (b,o). u[1152][16] in registers, 3 rows/thr.
// Writes v (out elem 0..40959) and one_hot (out elem 241664..244223).
__global__ __launch_bounds__(384) void k_routing(
        const unsigned short* __restrict__ caps, const void* __restrict__ Wd,
        const int* __restrict__ label, void* __restrict__ d_out,
        float* __restrict__ vsel, const int* __restrict__ flagp) {
    int f = *flagp;
    int bo = blockIdx.x;
    int b = bo / 10, o = bo - b * 10;
    int tid = threadIdx.x;
    int wid = tid >> 6, lane = tid & 63;

    __shared__ float redw[6][16];
    __shared__ float sbuf[16];
    __shared__ float mred[8];
    __shared__ float sred[8];

    float u[3][16];
    float a[3] = {0.f, 0.f, 0.f};
    const unsigned short* capb = caps + (size_t)b * 9216;

#pragma unroll
    for (int r = 0; r < 3; ++r) {
        int i = tid + r * 384;                       // covers 0..1151 exactly
        u16x8 cq = *(const u16x8*)(capb + i * 8);
        float cf[8];
#pragma unroll
        for (int d = 0; d < 8; ++d) cf[d] = clampf(bf2f(cq[d]), 100.f);
        size_t wbase = (size_t)(i * 10 + o) * 128;
        if (f) {
            const float* wp = (const float*)Wd + wbase;
#pragma unroll
            for (int n = 0; n < 16; ++n) {
                float sacc = 0.f;
#pragma unroll
                for (int d = 0; d < 8; ++d)
                    sacc += clampf(wp[n * 8 + d], 1000.f) * cf[d];
                u[r][n] = clampf(sacc, 1.0e6f);
            }
        } else {
            const u16x8* wq = (const u16x8*)((const unsigned short*)Wd + wbase);
#pragma unroll
            for (int n = 0; n < 16; ++n) {
                u16x8 q = wq[n];
                float sacc = 0.f;
#pragma unroll
                for (int d = 0; d < 8; ++d)
                    sacc += clampf(bf2f(q[d]), 1000.f) * cf[d];
                u[r][n] = clampf(sacc, 1.0e6f);
            }
        }
    }

    for (int rr = 1; rr <= 3; ++rr) {
        // --- softmax over i (1152) of logits a ---
        float mx = fmaxf(fmaxf(a[0], a[1]), a[2]);
#pragma unroll
        for (int off = 32; off; off >>= 1) mx = fmaxf(mx, __shfl_xor(mx, off));
        if (lane == 0) mred[wid] = mx;
        __syncthreads();
        float M = mred[0];
#pragma unroll
        for (int w = 1; w < 6; ++w) M = fmaxf(M, mred[w]);

        float e[3], es = 0.f;
#pragma unroll
        for (int r = 0; r < 3; ++r) { e[r] = __expf(a[r] - M); es += e[r]; }
#pragma unroll
        for (int off = 32; off; off >>= 1) es += __shfl_xor(es, off);
        if (lane == 0) sred[wid] = es;
        __syncthreads();
        float S = 0.f;
#pragma unroll
        for (int w = 0; w < 6; ++w) S += sred[w];
        float inv = 1.f / S;

        // --- s[n] = sum_i c_i * u[i][n] ---
        float p[16];
#pragma unroll
        for (int n = 0; n < 16; ++n)
            p[n] = (e[0] * u[0][n] + e[1] * u[1][n] + e[2] * u[2][n]) * inv;
#pragma unroll
        for (int n = 0; n < 16; ++n)
#pragma unroll
            for (int off = 32; off; off >>= 1) p[n] += __shfl_xor(p[n], off);
        if (lane == 0)
#pragma unroll
            for (int n = 0; n < 16; ++n) redw[wid][n] = p[n];
        __syncthreads();
        if (tid < 16) {
            float sn = 0.f;
#pragma unroll
            for (int w = 0; w < 6; ++w) sn += redw[w][tid];
            sbuf[tid] = clampf(sn, 3.0e9f);
        }
        __syncthreads();

        float ss = 0.f;
#pragma unroll
        for (int n = 0; n < 16; ++n) ss += sbuf[n] * sbuf[n];
        float sc = sqrtf(ss) / (1.f + ss);

        if (rr < 3) {
#pragma unroll
            for (int r = 0; r < 3; ++r) {
                float dot = 0.f;
#pragma unroll
                for (int n = 0; n < 16; ++n) dot += sbuf[n] * u[r][n];
                a[r] += sc * dot;
            }
            __syncthreads();
        } else {
            int lbl = label[b];
            if (tid < 16) {
                float vn = clampf(sbuf[tid] * sc, 1.f);
                if (f) ((float*)d_out)[(bo << 4) + tid] = vn;
                else   ((unsigned short*)d_out)[(bo << 4) + tid] = f2bf(vn);
                if (o == lbl) vsel[(b << 4) + tid] = vn;
            }
            if (tid == 0) {
                float oh = (o == lbl) ? 1.f : 0.f;
                if (f) ((float*)d_out)[241664 + bo] = oh;
                else   ((unsigned short*)d_out)[241664 + bo] = f2bf(oh);
            }
        }
    }
}

// ---------------------------------------------------------------------------
// decoder layer 1: only 16 columns of W1 are live (masked input)
__global__ void k_dec1(const float* __restrict__ vsel, const int* __restrict__ label,
                       const void* __restrict__ w1, const void* __restrict__ b1,
                       float* __restrict__ r1, const int* __restrict__ flagp) {
    int f = *flagp;
    int b = blockIdx.x, j = threadIdx.x;   // 512 threads
    __shared__ float vs[16];
    if (j < 16) vs[j] = vsel[b * 16 + j];
    __syncthreads();
    int lbl = label[b];
    size_t wb = (size_t)j * 160 + lbl * 16;
    float acc = rdf(b1, j, f);
#pragma unroll
    for (int n = 0; n < 16; ++n) acc += rdf(w1, wb + n, f) * vs[n];
    r1[b * 512 + j] = fmaxf(acc, 0.f);     // scrubs NaN -> 0
}

__global__ void k_dec2(const float* __restrict__ r1,
                       const void* __restrict__ w2, const void* __restrict__ b2,
                       float* __restrict__ r2, const int* __restrict__ flagp) {
    int f = *flagp;
    int b = blockIdx.x, tid = threadIdx.x;
    __shared__ float rl[512];
    rl[tid] = r1[b * 512 + tid];
    rl[tid + 256] = r1[b * 512 + 256 + tid];
    __syncthreads();
    float acc[4];
#pragma unroll
    for (int q = 0; q < 4; ++q) acc[q] = rdf(b2, tid + q * 256, f);
    if (f) {
        const float* wf = (const float*)w2;
        for (int j = 0; j < 512; ++j) {
            float rj = rl[j];
#pragma unroll
            for (int q = 0; q < 4; ++q)
                acc[q] += wf[(size_t)(tid + q * 256) * 512 + j] * rj;
        }
    } else {
        const unsigned short* wu = (const unsigned short*)w2;
        for (int j = 0; j < 512; j += 2) {
            float ra = rl[j], rb = rl[j + 1];
#pragma unroll
            for (int q = 0; q < 4; ++q) {
                unsigned int wv = *(const unsigned int*)(wu + (size_t)(tid + q * 256) * 512 + j);
                acc[q] += bf2f((unsigned short)(wv & 0xffff)) * ra
                        + bf2f((unsigned short)(wv >> 16)) * rb;
            }
        }
    }
#pragma unroll
    for (int q = 0; q < 4; ++q)
        r2[b * 1024 + tid + q * 256] = fmaxf(acc[q], 0.f);   // scrubs NaN -> 0
}

// recon -> out elements [40960, 241664)
__global__ void k_dec3(const float* __restrict__ r2,
                       const void* __restrict__ w3, const void* __restrict__ b3,
                       void* __restrict__ d_out, const int* __restrict__ flagp) {
    int f = *flagp;
    int b = blockIdx.x, tid = threadIdx.x;
    __shared__ float rl[1024];
#pragma unroll
    for (int q = 0; q < 4; ++q) rl[tid + q * 256] = r2[b * 1024 + tid + q * 256];
    __syncthreads();
#pragma unroll
    for (int q = 0; q < 4; ++q) {
        int p = tid + q * 256;
        if (p < 784) {
            float acc = rdf(b3, p, f);
            if (f) {
                const float* wf = (const float*)w3 + (size_t)p * 1024;
                for (int j = 0; j < 1024; ++j) acc += wf[j] * rl[j];
            } else {
                const unsigned short* wu = (const unsigned short*)w3 + (size_t)p * 1024;
                for (int j = 0; j < 1024; j += 2) {
                    unsigned int wv = *(const unsigned int*)(wu + j);
                    acc += bf2f((unsigned short)(wv & 0xffff)) * rl[j]
                         + bf2f((unsigned short)(wv >> 16)) * rl[j + 1];
                }
            }
            acc = clampf(acc, 60.f);       // scrubs NaN; |real acc| << 60
            float sig = 1.f / (1.f + __expf(-acc));
            size_t oi = 40960 + (size_t)b * 784 + p;
            if (f) ((float*)d_out)[oi] = sig;
            else   ((unsigned short*)d_out)[oi] = f2bf(sig);
        }
    }
}

// ---------------------------------------------------------------------------
extern "C" void kernel_launch(void* const* d_in, const int* in_sizes, int n_in,
                              void* d_out, int out_size, void* d_ws, size_t ws_size,
                              hipStream_t stream) {
    const void* x    = d_in[0];
    const int*  lbl  = (const int*)d_in[1];
    const void* w1c  = d_in[2];
    const void* b1c  = d_in[3];
    const void* w2c  = d_in[4];
    const void* b2c  = d_in[5];
    const void* wdig = d_in[6];
    const void* dw1  = d_in[7];
    const void* db1  = d_in[8];
    const void* dw2  = d_in[9];
    const void* db2  = d_in[10];
    const void* dw3  = d_in[11];
    const void* db3  = d_in[12];
    (void)in_sizes; (void)n_in; (void)out_size;

    char* ws = (char*)d_ws;
    // Fixed pool, 256B-aligned offsets; total fixed = 21,694,464 B (~20.7 MiB)
    int* flagp           = (int*)(ws);                        // 256 B
    unsigned short* B1p  = (unsigned short*)(ws + 256);       // 49,152
    unsigned short* Bp2  = (unsigned short*)(ws + 49664);     // 10,616,832
    unsigned short* h2   = (unsigned short*)(ws + 10666752);  // 4,718,592
    unsigned short* caps = (unsigned short*)(ws + 15385600);  // 4,718,592
    float* vsel          = (float*)(ws + 20104448);           // 16,384
    float* r1            = (float*)(ws + 20121088);           // 524,288
    float* r2            = (float*)(ws + 20645632);           // 1,048,576
    unsigned short* h1p  = (unsigned short*)(ws + 21694464);  // C*204,800

    const size_t fixed = 21694464;
    int C = 16;
    const int cands[5] = {256, 128, 64, 32, 16};
    for (int ci = 0; ci < 5; ++ci)
        if (fixed + (size_t)cands[ci] * 204800 <= ws_size) { C = cands[ci]; break; }

    hipLaunchKernelGGL(k_detect,    dim3(1),     dim3(64),  0, stream, w1c, flagp);
    hipLaunchKernelGGL(k_repack_w1, dim3(96),    dim3(256), 0, stream, w1c, B1p, flagp);
    hipLaunchKernelGGL(k_repack_w2, dim3(20736), dim3(256), 0, stream, w2c, Bp2, flagp);

    int nchunk = 256 / C;
    for (int c = 0; c < nchunk; ++c) {
        int b0 = c * C;
        hipLaunchKernelGGL(k_conv1, dim3(25 * C / 8, 2), dim3(256), 0, stream,
                           x, B1p, b1c, h1p, b0, flagp);
        hipLaunchKernelGGL(k_conv2, dim3(9 * C / 16, 2), dim3(256), 0, stream,
                           h1p, Bp2, h2, b0);
    }

    hipLaunchKernelGGL(k_caps,    dim3(1152), dim3(256), 0, stream, h2, b2c, caps, flagp);
    hipLaunchKernelGGL(k_routing, dim3(2560), dim3(384), 0, stream, caps, wdig, lbl,
                       d_out, vsel, flagp);
    hipLaunchKernelGGL(k_dec1,    dim3(256),  dim3(512), 0, stream, vsel, lbl, dw1, db1, r1, flagp);
    hipLaunchKernelGGL(k_dec2,    dim3(256),  dim3(256), 0, stream, r1, dw2, db2, r2, flagp);
    hipLaunchKernelGGL(k_dec3,    dim3(256),  dim3(256), 0, stream, r2, dw3, db3, d_out, flagp);
}

// Round 5
// 1010.222 us; speedup vs baseline: 1.4448x; 1.4448x over previous
//
#include <hip/hip_runtime.h>
#include <hip/hip_bf16.h>
#include <stdint.h>

// ---------------------------------------------------------------------------
// CapsuleNet forward, MI355X gfx950.  Round 5 (first passing round was R4 at
// 1459 us; conv2 863 us latency-bound at 8.9% occupancy).
//  * conv2: 128x128 tiles (64x64 wave tiles), K-split S=8 over taps ->
//    grid (72,2,8)=1152 blocks, fp32 atomicAdd into zeroed h2f.
//  * conv1: source image(s) staged in LDS as bf16; A-frags gathered from LDS.
//  * repack_w2: coalesced read + LDS transpose per co.
//  * dtype detector (fp32-vs-bf16) retained; NaN clamps retained.
//  * ws: 72.5 MB (known ws_size >= 74.12 MB from R4's C=256 selection).
// ---------------------------------------------------------------------------

typedef short short8 __attribute__((ext_vector_type(8)));
typedef unsigned short u16x8 __attribute__((ext_vector_type(8)));
typedef float f32x4  __attribute__((ext_vector_type(4)));

__device__ inline float bf2f(unsigned short u) {
    unsigned int v = ((unsigned int)u) << 16;
    float f;
    __builtin_memcpy(&f, &v, 4);
    return f;
}
__device__ inline unsigned short f2bf(float f) {
    __hip_bfloat16 h = __float2bfloat16(f);
    unsigned short u;
    __builtin_memcpy(&u, &h, 2);
    return u;
}
__device__ inline float clampf(float x, float b) {   // scrubs NaN -> -b
    return fminf(fmaxf(x, -b), b);
}
// flag-aware float read: f=1 -> fp32 buffer, f=0 -> bf16 buffer
__device__ inline float rdf(const void* p, size_t i, int f) {
    return f ? ((const float*)p)[i] : bf2f(((const unsigned short*)p)[i]);
}

// ---------------------------------------------------------------------------
// Detect input float dtype from conv1_w (values ~N(0,0.05)).
__global__ void k_detect(const void* w, int* flag) {
    int lane = threadIdx.x;                       // 64 threads
    const unsigned short* u = (const unsigned short*)w;
    int cnt = 0;
#pragma unroll
    for (int j = 0; j < 4; ++j) {
        float v = fabsf(bf2f(u[lane * 4 + j]));
        if (v > 100.f) cnt++;
    }
#pragma unroll
    for (int off = 32; off; off >>= 1) cnt += __shfl_xor(cnt, off);
    if (lane == 0) flag[0] = (cnt >= 4) ? 1 : 0;
}

__global__ void k_zero(float* __restrict__ p) {    // 2304 x 256: zero h2f
    int i = blockIdx.x * 256 + threadIdx.x;
    ((f32x4*)p)[i] = (f32x4){0.f, 0.f, 0.f, 0.f};
}

// ---------------------------------------------------------------------------
__global__ void k_repack_w1(const void* __restrict__ w,
                            unsigned short* __restrict__ B1p,
                            const int* __restrict__ flagp) {
    int f = *flagp;
    int idx = blockIdx.x * 256 + threadIdx.x;      // 256*96
    int co = idx / 96, k = idx - co * 96;
    B1p[idx] = (k < 81) ? f2bf(rdf(w, (size_t)co * 81 + k, f)) : (unsigned short)0;
}

// pconv_w [co][ci][81] -> Bp2[t][co][ci] (bf16). One block per co:
// coalesced read of 20736 floats -> LDS [ci][t] -> contiguous 512B writes.
__global__ __launch_bounds__(256) void k_repack_w2(
        const void* __restrict__ w, unsigned short* __restrict__ Bp,
        const int* __restrict__ flagp) {
    __shared__ unsigned short wl[20736];           // 256 ci x 81 t, 41.5 KB
    int f = *flagp;
    int co = blockIdx.x;
    int tid = threadIdx.x;
    size_t base = (size_t)co * 20736;
    for (int i = tid; i < 20736; i += 256)
        wl[i] = f2bf(rdf(w, base + i, f));         // wl[ci*81+t]
    __syncthreads();
    unsigned short* out = Bp + (co << 8) + tid;    // [t][co][ci=tid]
#pragma unroll 3
    for (int t = 0; t < 81; ++t)
        out[(size_t)t << 16] = wl[tid * 81 + t];
}

// ---------------------------------------------------------------------------
// conv1: C[102400,256] = im2col(x) * B1p^T, 128x128 tiles, x staged in LDS.
// Frag layouts (m89/m91-verified): A: m=lane&15, k=(lane>>4)*8+j
//                                  B: n=lane&15, k=(lane>>4)*8+j
//                                  C: col=lane&15, row=(lane>>4)*4+reg
__global__ __launch_bounds__(256) void k_conv1(
        const void* __restrict__ x,
        const unsigned short* __restrict__ B1p,
        const void* __restrict__ bias,
        unsigned short* __restrict__ h1p,
        const int* __restrict__ flagp) {
    __shared__ unsigned short xl[1568];            // up to 2 images, bf16
    __shared__ int offt[96];
    int f = *flagp;
    int tid = threadIdx.x;
    if (tid < 96) offt[tid] = (tid < 81) ? (tid / 9) * 28 + (tid % 9) : 0;

    int mblk = blockIdx.x * 128;
    int bfirst = mblk / 400;
    int blast = (mblk + 127) / 400;
    int nload = (blast - bfirst + 1) * 784;
    for (int i = tid; i < nload; i += 256)
        xl[i] = f2bf(rdf(x, (size_t)bfirst * 784 + i, f));
    __syncthreads();

    int wave = tid >> 6, lane = tid & 63;
    int wr = wave >> 1, wc = wave & 1;
    int mbase = mblk + wr * 64;
    int nbase = blockIdx.y * 128 + wc * 64;
    int l15 = lane & 15, l4 = lane >> 4;

    int lbase[4];
#pragma unroll
    for (int mt = 0; mt < 4; ++mt) {
        int m = mbase + mt * 16 + l15;
        int img = m / 400 - bfirst, pos = m % 400;
        lbase[mt] = img * 784 + (pos / 20) * 28 + (pos % 20);
    }

    f32x4 acc[4][4];
#pragma unroll
    for (int mt = 0; mt < 4; ++mt)
#pragma unroll
        for (int nt = 0; nt < 4; ++nt)
            acc[mt][nt] = (f32x4){0.f, 0.f, 0.f, 0.f};

#pragma unroll
    for (int kc = 0; kc < 3; ++kc) {
        int kbase = kc * 32 + l4 * 8;
        short8 af[4], bfr[4];
#pragma unroll
        for (int mt = 0; mt < 4; ++mt)
#pragma unroll
            for (int j = 0; j < 8; ++j) {
                int k = kbase + j;
                af[mt][j] = (k < 81) ? (short)xl[lbase[mt] + offt[k]] : (short)0;
            }
#pragma unroll
        for (int nt = 0; nt < 4; ++nt)
            bfr[nt] = *(const short8*)(B1p + (size_t)(nbase + nt * 16 + l15) * 96 + kbase);
#pragma unroll
        for (int mt = 0; mt < 4; ++mt)
#pragma unroll
            for (int nt = 0; nt < 4; ++nt)
                acc[mt][nt] = __builtin_amdgcn_mfma_f32_16x16x32_bf16(
                    af[mt], bfr[nt], acc[mt][nt], 0, 0, 0);
    }

#pragma unroll
    for (int mt = 0; mt < 4; ++mt)
#pragma unroll
        for (int nt = 0; nt < 4; ++nt) {
            int col = nbase + nt * 16 + l15;
            float bv = rdf(bias, col, f);
#pragma unroll
            for (int r = 0; r < 4; ++r) {
                int row = mbase + mt * 16 + l4 * 4 + r;
                h1p[(size_t)row * 256 + col] = f2bf(clampf(acc[mt][nt][r] + bv, 1024.f));
            }
        }
}

// ---------------------------------------------------------------------------
// conv2: implicit im2col GEMM, 128x128 tiles (64x64 wave tiles), K-split S=8
// over taps, fp32 atomicAdd into h2f. grid (72, 2, 8).
__global__ __launch_bounds__(256) void k_conv2(
        const unsigned short* __restrict__ h1p,
        const unsigned short* __restrict__ Bp,
        float* __restrict__ h2f) {
    int tid = threadIdx.x;
    int wave = tid >> 6, lane = tid & 63;
    int wr = wave >> 1, wc = wave & 1;
    int mbase = blockIdx.x * 128 + wr * 64;
    int nbase = blockIdx.y * 128 + wc * 64;
    int s = blockIdx.z;
    int t0 = (81 * s) >> 3, t1 = (81 * (s + 1)) >> 3;
    int l15 = lane & 15, l4 = lane >> 4;

    int rowoff[4];
#pragma unroll
    for (int mt = 0; mt < 4; ++mt) {
        int m = mbase + mt * 16 + l15;
        int bb = m / 36, pos = m - bb * 36;
        int y = pos / 6, xx = pos - y * 6;
        rowoff[mt] = (bb * 400 + y * 40 + xx * 2) * 256;   // (bb,2y,2x) NHWC
    }
    int koff = l4 * 8;

    f32x4 acc[4][4];
#pragma unroll
    for (int mt = 0; mt < 4; ++mt)
#pragma unroll
        for (int nt = 0; nt < 4; ++nt)
            acc[mt][nt] = (f32x4){0.f, 0.f, 0.f, 0.f};

    for (int t = t0; t < t1; ++t) {
        int ky = t / 9, kx = t - ky * 9;
        int tadd = (ky * 20 + kx) * 256;
        const unsigned short* brow = Bp + ((size_t)t << 16) + (size_t)nbase * 256;
#pragma unroll
        for (int kc = 0; kc < 8; ++kc) {
            int k0 = kc * 32 + koff;
            short8 af[4], bfr[4];
#pragma unroll
            for (int mt = 0; mt < 4; ++mt)
                af[mt] = *(const short8*)(h1p + rowoff[mt] + tadd + k0);
#pragma unroll
            for (int nt = 0; nt < 4; ++nt)
                bfr[nt] = *(const short8*)(brow + (nt * 16 + l15) * 256 + k0);
#pragma unroll
            for (int mt = 0; mt < 4; ++mt)
#pragma unroll
                for (int nt = 0; nt < 4; ++nt)
                    acc[mt][nt] = __builtin_amdgcn_mfma_f32_16x16x32_bf16(
                        af[mt], bfr[nt], acc[mt][nt], 0, 0, 0);
        }
    }

#pragma unroll
    for (int mt = 0; mt < 4; ++mt)
#pragma unroll
        for (int nt = 0; nt < 4; ++nt) {
            int col = nbase + nt * 16 + l15;
#pragma unroll
            for (int r = 0; r < 4; ++r) {
                int row = mbase + mt * 16 + l4 * 4 + r;
                atomicAdd(&h2f[(size_t)row * 256 + col], acc[mt][nt][r]);
            }
        }
}

// ---------------------------------------------------------------------------
// +bias, regroup [b][co][pos] into caps of 8, squash -> caps bf16
__global__ void k_caps(const float* __restrict__ h2f,
                       const void* __restrict__ pb,
                       unsigned short* __restrict__ caps,
                       const int* __restrict__ flagp) {
    int f = *flagp;
    int g = blockIdx.x * 256 + threadIdx.x;   // 256*1152
    int b = g / 1152, i = g - b * 1152;
    float h[8], ss = 0.f;
#pragma unroll
    for (int d = 0; d < 8; ++d) {
        int flat = i * 8 + d;                 // = co*36 + pos
        int co = flat / 36, pos = flat - co * 36;
        float v = clampf(h2f[(size_t)(b * 36 + pos) * 256 + co] + rdf(pb, co, f), 20000.f);
        h[d] = v;
        ss += v * v;
    }
    float sc = sqrtf(ss) / (1.f + ss);        // norm/(1+norm^2)
    u16x8 cv;
#pragma unroll
    for (int d = 0; d < 8; ++d) cv[d] = f2bf(h[d] * sc);
    *(u16x8*)(caps + (size_t)g * 8) = cv;
}

// ---------------------------------------------------------------------------
// Dynamic routing. One block per (b,o). u[1152][16] in registers, 3 rows/thr.
__global__ __launch_bounds__(384) void k_routing(
        const unsigned short* __restrict__ caps, const void* __restrict__ Wd,
        const int* __restrict__ label, void* __restrict__ d_out,
        float* __restrict__ vsel, const int* __restrict__ flagp) {
    int f = *flagp;
    int bo = blockIdx.x;
    int b = bo / 10, o = bo - b * 10;
    int tid = threadIdx.x;
    int wid = tid >> 6, lane = tid & 63;

    __shared__ float redw[6][16];
    __shared__ float sbuf[16];
    __shared__ float mred[8];
    __shared__ float sred[8];

    float u[3][16];
    float a[3] = {0.f, 0.f, 0.f};
    const unsigned short* capb = caps + (size_t)b * 9216;

#pragma unroll
    for (int r = 0; r < 3; ++r) {
        int i = tid + r * 384;                       // covers 0..1151 exactly
        u16x8 cq = *(const u16x8*)(capb + i * 8);
        float cf[8];
#pragma unroll
        for (int d = 0; d < 8; ++d) cf[d] = clampf(bf2f(cq[d]), 100.f);
        size_t wbase = (size_t)(i * 10 + o) * 128;
        if (f) {
            const float* wp = (const float*)Wd + wbase;
#pragma unroll
            for (int n = 0; n < 16; ++n) {
                float sacc = 0.f;
#pragma unroll
                for (int d = 0; d < 8; ++d)
                    sacc += clampf(wp[n * 8 + d], 1000.f) * cf[d];
                u[r][n] = clampf(sacc, 1.0e6f);
            }
        } else {
            const u16x8* wq = (const u16x8*)((const unsigned short*)Wd + wbase);
#pragma unroll
            for (int n = 0; n < 16; ++n) {
                u16x8 q = wq[n];
                float sacc = 0.f;
#pragma unroll
                for (int d = 0; d < 8; ++d)
                    sacc += clampf(bf2f(q[d]), 1000.f) * cf[d];
                u[r][n] = clampf(sacc, 1.0e6f);
            }
        }
    }

    for (int rr = 1; rr <= 3; ++rr) {
        float mx = fmaxf(fmaxf(a[0], a[1]), a[2]);
#pragma unroll
        for (int off = 32; off; off >>= 1) mx = fmaxf(mx, __shfl_xor(mx, off));
        if (lane == 0) mred[wid] = mx;
        __syncthreads();
        float M = mred[0];
#pragma unroll
        for (int w = 1; w < 6; ++w) M = fmaxf(M, mred[w]);

        float e[3], es = 0.f;
#pragma unroll
        for (int r = 0; r < 3; ++r) { e[r] = __expf(a[r] - M); es += e[r]; }
#pragma unroll
        for (int off = 32; off; off >>= 1) es += __shfl_xor(es, off);
        if (lane == 0) sred[wid] = es;
        __syncthreads();
        float S = 0.f;
#pragma unroll
        for (int w = 0; w < 6; ++w) S += sred[w];
        float inv = 1.f / S;

        float p[16];
#pragma unroll
        for (int n = 0; n < 16; ++n)
            p[n] = (e[0] * u[0][n] + e[1] * u[1][n] + e[2] * u[2][n]) * inv;
#pragma unroll
        for (int n = 0; n < 16; ++n)
#pragma unroll
            for (int off = 32; off; off >>= 1) p[n] += __shfl_xor(p[n], off);
        if (lane == 0)
#pragma unroll
            for (int n = 0; n < 16; ++n) redw[wid][n] = p[n];
        __syncthreads();
        if (tid < 16) {
            float sn = 0.f;
#pragma unroll
            for (int w = 0; w < 6; ++w) sn += redw[w][tid];
            sbuf[tid] = clampf(sn, 3.0e9f);
        }
        __syncthreads();

        float ss = 0.f;
#pragma unroll
        for (int n = 0; n < 16; ++n) ss += sbuf[n] * sbuf[n];
        float sc = sqrtf(ss) / (1.f + ss);

        if (rr < 3) {
#pragma unroll
            for (int r = 0; r < 3; ++r) {
                float dot = 0.f;
#pragma unroll
                for (int n = 0; n < 16; ++n) dot += sbuf[n] * u[r][n];
                a[r] += sc * dot;
            }
            __syncthreads();
        } else {
            int lbl = label[b];
            if (tid < 16) {
                float vn = clampf(sbuf[tid] * sc, 1.f);
                if (f) ((float*)d_out)[(bo << 4) + tid] = vn;
                else   ((unsigned short*)d_out)[(bo << 4) + tid] = f2bf(vn);
                if (o == lbl) vsel[(b << 4) + tid] = vn;
            }
            if (tid == 0) {
                float oh = (o == lbl) ? 1.f : 0.f;
                if (f) ((float*)d_out)[241664 + bo] = oh;
                else   ((unsigned short*)d_out)[241664 + bo] = f2bf(oh);
            }
        }
    }
}

// ---------------------------------------------------------------------------
__global__ void k_dec1(const float* __restrict__ vsel, const int* __restrict__ label,
                       const void* __restrict__ w1, const void* __restrict__ b1,
                       float* __restrict__ r1, const int* __restrict__ flagp) {
    int f = *flagp;
    int b = blockIdx.x, j = threadIdx.x;   // 512 threads
    __shared__ float vs[16];
    if (j < 16) vs[j] = vsel[b * 16 + j];
    __syncthreads();
    int lbl = label[b];
    size_t wb = (size_t)j * 160 + lbl * 16;
    float acc = rdf(b1, j, f);
#pragma unroll
    for (int n = 0; n < 16; ++n) acc += rdf(w1, wb + n, f) * vs[n];
    r1[b * 512 + j] = fmaxf(acc, 0.f);     // scrubs NaN -> 0
}

__global__ void k_dec2(const float* __restrict__ r1,
                       const void* __restrict__ w2, const void* __restrict__ b2,
                       float* __restrict__ r2, const int* __restrict__ flagp) {
    int f = *flagp;
    int b = blockIdx.x, tid = threadIdx.x;
    __shared__ float rl[512];
    rl[tid] = r1[b * 512 + tid];
    rl[tid + 256] = r1[b * 512 + 256 + tid];
    __syncthreads();
    float acc[4];
#pragma unroll
    for (int q = 0; q < 4; ++q) acc[q] = rdf(b2, tid + q * 256, f);
    if (f) {
        const float* wf = (const float*)w2;
        for (int j = 0; j < 512; ++j) {
            float rj = rl[j];
#pragma unroll
            for (int q = 0; q < 4; ++q)
                acc[q] += wf[(size_t)(tid + q * 256) * 512 + j] * rj;
        }
    } else {
        const unsigned short* wu = (const unsigned short*)w2;
        for (int j = 0; j < 512; j += 2) {
            float ra = rl[j], rb = rl[j + 1];
#pragma unroll
            for (int q = 0; q < 4; ++q) {
                unsigned int wv = *(const unsigned int*)(wu + (size_t)(tid + q * 256) * 512 + j);
                acc[q] += bf2f((unsigned short)(wv & 0xffff)) * ra
                        + bf2f((unsigned short)(wv >> 16)) * rb;
            }
        }
    }
#pragma unroll
    for (int q = 0; q < 4; ++q)
        r2[b * 1024 + tid + q * 256] = fmaxf(acc[q], 0.f);   // scrubs NaN -> 0
}

__global__ void k_dec3(const float* __restrict__ r2,
                       const void* __restrict__ w3, const void* __restrict__ b3,
                       void* __restrict__ d_out, const int* __restrict__ flagp) {
    int f = *flagp;
    int b = blockIdx.x, tid = threadIdx.x;
    __shared__ float rl[1024];
#pragma unroll
    for (int q = 0; q < 4; ++q) rl[tid + q * 256] = r2[b * 1024 + tid + q * 256];
    __syncthreads();
#pragma unroll
    for (int q = 0; q < 4; ++q) {
        int p = tid + q * 256;
        if (p < 784) {
            float acc = rdf(b3, p, f);
            if (f) {
                const float* wf = (const float*)w3 + (size_t)p * 1024;
                for (int j = 0; j < 1024; ++j) acc += wf[j] * rl[j];
            } else {
                const unsigned short* wu = (const unsigned short*)w3 + (size_t)p * 1024;
                for (int j = 0; j < 1024; j += 2) {
                    unsigned int wv = *(const unsigned int*)(wu + j);
                    acc += bf2f((unsigned short)(wv & 0xffff)) * rl[j]
                         + bf2f((unsigned short)(wv >> 16)) * rl[j + 1];
                }
            }
            acc = clampf(acc, 60.f);
            float sig = 1.f / (1.f + __expf(-acc));
            size_t oi = 40960 + (size_t)b * 784 + p;
            if (f) ((float*)d_out)[oi] = sig;
            else   ((unsigned short*)d_out)[oi] = f2bf(sig);
        }
    }
}

// ---------------------------------------------------------------------------
extern "C" void kernel_launch(void* const* d_in, const int* in_sizes, int n_in,
                              void* d_out, int out_size, void* d_ws, size_t ws_size,
                              hipStream_t stream) {
    const void* x    = d_in[0];
    const int*  lbl  = (const int*)d_in[1];
    const void* w1c  = d_in[2];
    const void* b1c  = d_in[3];
    const void* w2c  = d_in[4];
    const void* b2c  = d_in[5];
    const void* wdig = d_in[6];
    const void* dw1  = d_in[7];
    const void* db1  = d_in[8];
    const void* dw2  = d_in[9];
    const void* db2  = d_in[10];
    const void* dw3  = d_in[11];
    const void* db3  = d_in[12];
    (void)in_sizes; (void)n_in; (void)out_size; (void)ws_size;

    char* ws = (char*)d_ws;
    // Layout (72.5 MB total; ws_size >= 74.12 MB deduced from R4):
    int* flagp           = (int*)(ws);                        // 256 B
    float* h2f           = (float*)(ws + 256);                // 9,437,184
    unsigned short* Bp2  = (unsigned short*)(ws + 9437440);   // 10,616,832
    //   After conv2, Bp2 region is dead; overlay routing/decoder scratch:
    unsigned short* caps = (unsigned short*)(ws + 9437440);   // 4,718,592
    float* vsel          = (float*)(ws + 14156032);           // 16,384
    float* r1            = (float*)(ws + 14172416);           // 524,288
    float* r2            = (float*)(ws + 14696704);           // 1,048,576
    unsigned short* B1p  = (unsigned short*)(ws + 20054272);  // 49,152
    unsigned short* h1p  = (unsigned short*)(ws + 20103424);  // 52,428,800 -> 72,532,224

    hipLaunchKernelGGL(k_detect,    dim3(1),    dim3(64),  0, stream, w1c, flagp);
    hipLaunchKernelGGL(k_zero,      dim3(2304), dim3(256), 0, stream, h2f);
    hipLaunchKernelGGL(k_repack_w1, dim3(96),   dim3(256), 0, stream, w1c, B1p, flagp);
    hipLaunchKernelGGL(k_repack_w2, dim3(256),  dim3(256), 0, stream, w2c, Bp2, flagp);

    hipLaunchKernelGGL(k_conv1, dim3(800, 2),   dim3(256), 0, stream, x, B1p, b1c, h1p, flagp);
    hipLaunchKernelGGL(k_conv2, dim3(72, 2, 8), dim3(256), 0, stream, h1p, Bp2, h2f);

    hipLaunchKernelGGL(k_caps,    dim3(1152), dim3(256), 0, stream, h2f, b2c, caps, flagp);
    hipLaunchKernelGGL(k_routing, dim3(2560), dim3(384), 0, stream, caps, wdig, lbl,
                       d_out, vsel, flagp);
    hipLaunchKernelGGL(k_dec1,    dim3(256),  dim3(512), 0, stream, vsel, lbl, dw1, db1, r1, flagp);
    hipLaunchKernelGGL(k_dec2,    dim3(256),  dim3(256), 0, stream, r1, dw2, db2, r2, flagp);
    hipLaunchKernelGGL(k_dec3,    dim3(256),  dim3(256), 0, stream, r2, dw3, db3, d_out, flagp);
}